// Round 12
// baseline (653.571 us; speedup 1.0000x reference)
//
#include <hip/hip_runtime.h>
#include <math.h>

#define M_SEQ 11520   // B*N
#define NNODE 360
#define NB    32
#define TT    64

// adj path: libm-accurate — the gumbel/argmax pipeline stays bit-identical
// to the proven-passing state (R5..R11).
// GRU + decode: fast hardware exp. GRU drift enters feat at ~1e-6 ->
// ~2-5% argmax-flip risk across 11520 rows (calculated gamble, revertible).
__device__ __forceinline__ float fsigd(float x)  { return 1.0f / (1.0f + __expf(-x)); }
__device__ __forceinline__ float ftanhd(float x) { return 1.0f - 2.0f / (__expf(2.0f * x) + 1.0f); }

// ---------------- JAX threefry2x32, key=(0,42), partitionable, bits=y0^y1 ----
__device__ __forceinline__ unsigned rotl32(unsigned x, int n) { return (x << n) | (x >> (32 - n)); }

__device__ __forceinline__ void tf2x32(unsigned& x0, unsigned& x1)
{
    const unsigned k0 = 0u, k1 = 42u, k2 = 0u ^ 42u ^ 0x1BD11BDAu;
    x0 += k0; x1 += k1;
#define R4(a,b,c,d) \
    x0 += x1; x1 = rotl32(x1,a); x1 ^= x0; \
    x0 += x1; x1 = rotl32(x1,b); x1 ^= x0; \
    x0 += x1; x1 = rotl32(x1,c); x1 ^= x0; \
    x0 += x1; x1 = rotl32(x1,d); x1 ^= x0;
    R4(13,15,26,6)   x0 += k1; x1 += k2 + 1u;
    R4(17,29,16,24)  x0 += k2; x1 += k0 + 2u;
    R4(13,15,26,6)   x0 += k0; x1 += k1 + 3u;
    R4(17,29,16,24)  x0 += k1; x1 += k2 + 4u;
    R4(13,15,26,6)   x0 += k2; x1 += k0 + 5u;
#undef R4
}

__device__ __forceinline__ float jax_uniform(unsigned idx)
{
    unsigned x0 = 0u, x1 = idx;
    tf2x32(x0, x1);
    unsigned bits = x0 ^ x1;          // VERIFIED R5
    return __uint_as_float((bits >> 9) | 0x3f800000u) - 1.0f;
}

// broadcast within aligned 8-lane group via static-pattern ds_swizzle.
template<int K>
__device__ __forceinline__ void swz_fma(float h, const float* w0, const float* w1,
                                        const float* w2, float& g0, float& g1, float& g2)
{
    float hk = __int_as_float(
        __builtin_amdgcn_ds_swizzle(__float_as_int(h), (K << 5) | 0x18));
    g0 += hk * w0[K];
    g1 += hk * w1[K];
    g2 += hk * w2[K];
    if constexpr (K < 7)
        swz_fma<K + 1>(h, w0, w1, w2, g0, g1, g2);
}

// ---------------- fused bidirectional GRU layer -----------------------------
template<int I>
__global__ __launch_bounds__(256) void gru_fused(
    const float* __restrict__ x,    // (M,64,I)
    const float* __restrict__ wih,  // (2,24,I)
    const float* __restrict__ whh,  // (2,24,8)
    const float* __restrict__ bih,  // (2,24)
    const float* __restrict__ bhh,  // (2,24)
    float* __restrict__ out)        // (M,64,16), dir writes its 8-half
{
    const int tid = blockIdx.x * 256 + threadIdx.x;
    const int j   = tid & 7;
    const int md  = tid >> 3;
    if (md >= M_SEQ * 2) return;
    const int m = md >> 1, dir = md & 1;

    float wx0[I], wx1[I], wx2[I];
    const float* WI = wih + dir * 24 * I;
#pragma unroll
    for (int k = 0; k < I; ++k) {
        wx0[k] = WI[j * I + k];
        wx1[k] = WI[(8 + j) * I + k];
        wx2[k] = WI[(16 + j) * I + k];
    }
    float w0[8], w1[8], w2[8];
    const float* WH = whh + dir * 192;
#pragma unroll
    for (int k = 0; k < 8; ++k) {
        w0[k] = WH[j * 8 + k];
        w1[k] = WH[(8 + j) * 8 + k];
        w2[k] = WH[(16 + j) * 8 + k];
    }
    const float bx0 = bih[dir*24 + j], bx1 = bih[dir*24 + 8 + j], bx2 = bih[dir*24 + 16 + j];
    const float bh0 = bhh[dir*24 + j], bh1 = bhh[dir*24 + 8 + j], bh2 = bhh[dir*24 + 16 + j];

    const float* xm = x + (size_t)m * TT * I;
    float* om = out + (size_t)m * TT * 16 + dir * 8 + j;

    float h = 0.f;
    for (int tt = 0; tt < TT; ++tt) {
        const int t = dir ? (TT - 1 - tt) : tt;
        float xv[I];
        const float4* xp4 = reinterpret_cast<const float4*>(xm + t * I);
#pragma unroll
        for (int q = 0; q < I / 4; ++q) {
            float4 f = xp4[q];
            xv[4*q] = f.x; xv[4*q+1] = f.y; xv[4*q+2] = f.z; xv[4*q+3] = f.w;
        }
        float xr = bx0, xz = bx1, xn = bx2;
#pragma unroll
        for (int k = 0; k < I; ++k) {
            xr += xv[k] * wx0[k];
            xz += xv[k] * wx1[k];
            xn += xv[k] * wx2[k];
        }
        float gh0 = bh0, gh1 = bh1, gh2 = bh2;
        swz_fma<0>(h, w0, w1, w2, gh0, gh1, gh2);
        float r  = fsigd(xr + gh0);
        float z  = fsigd(xz + gh1);
        float nn = ftanhd(xn + r * gh2);
        h = (1.f - z) * nn + z * h;
        om[t * 16] = h;
    }
}

// ---------------- feat MLP (pure FMA, no transcendentals) -------------------
__global__ void feat_kernel(const float* __restrict__ gout,
                            const float* __restrict__ l1w, const float* __restrict__ l1b,
                            const float* __restrict__ l2w, const float* __restrict__ l2b,
                            float* __restrict__ feat)
{
    int m = blockIdx.x * blockDim.x + threadIdx.x;
    if (m >= M_SEQ) return;
    const float* xp = gout + (size_t)m * TT * 16 + (TT - 1) * 16;
    float xv[16];
#pragma unroll
    for (int i = 0; i < 16; ++i) xv[i] = xp[i];
    float h1[8];
#pragma unroll
    for (int o = 0; o < 8; ++o) {
        float a = 0.f;
#pragma unroll
        for (int f = 0; f < 16; ++f) a += xv[f] * l1w[o * 16 + f];
        a += l1b[o];
        h1[o] = (a >= 0.f) ? a : 0.2f * a;
    }
#pragma unroll
    for (int o = 0; o < 8; ++o) {
        float a = 0.f;
#pragma unroll
        for (int f = 0; f < 8; ++f) a += h1[f] * l2w[o * 8 + f];
        feat[(size_t)m * 8 + o] = a + l2b[o];
    }
}

// ---------------- adjacency (libm — bit-identical to proven state) ----------
__global__ void adj_kernel(const float* __restrict__ feat,
                           const float* __restrict__ tptr,
                           int* __restrict__ colp, float* __restrict__ vp)
{
    const int gw   = (blockIdx.x * blockDim.x + threadIdx.x) >> 6;
    const int lane = threadIdx.x & 63;
    if (gw >= NB * NNODE) return;
    const int b = gw / NNODE;
    const int n = gw - b * NNODE;
    const float T = tptr[0];
    const float* fb = feat + (size_t)b * NNODE * 8;
    float fn[8];
#pragma unroll
    for (int k = 0; k < 8; ++k) fn[k] = fb[(size_t)n * 8 + k];

    float sv[6];
    float mval = -3.0e38f; int midx = 1 << 30;
#pragma unroll
    for (int s = 0; s < 6; ++s) {
        int p = s * 64 + lane;
        float xs = -3.0e38f;
        if (p < NNODE) {
            const float* fp = fb + (size_t)p * 8;
            float d = 0.f;
#pragma unroll
            for (int k = 0; k < 8; ++k) d += fn[k] * fp[k];
            unsigned idx = (unsigned)gw * 360u + (unsigned)p;
            float u   = jax_uniform(idx);
            float gum = -logf(-logf(u + 1e-10f) + 1e-10f);
            xs = (d + gum) / T;
            if (xs > mval) { mval = xs; midx = p; }
        }
        sv[s] = xs;
    }
    for (int off = 32; off > 0; off >>= 1) {   // ties -> smaller index
        float ov = __shfl_xor(mval, off);
        int   oi = __shfl_xor(midx, off);
        if (ov > mval || (ov == mval && oi < midx)) { mval = ov; midx = oi; }
    }
    float ssum = 0.f;
#pragma unroll
    for (int s = 0; s < 6; ++s) {
        int p = s * 64 + lane;
        if (p < NNODE) ssum += expf(sv[s] - mval);
    }
    for (int off = 32; off > 0; off >>= 1) ssum += __shfl_xor(ssum, off);
    if (lane == 0) {
        float ys = 1.0f / ssum;
        float v  = ys + (1.0f - ys);
        if (midx == n) v = 0.0f;
        colp[gw] = midx;
        vp[gw]   = v;
    }
}

// ---------------- DCGRU 3-layer step: R11-proven structure ------------------
__device__ __forceinline__ float run3(
    float* __restrict__ s_o, float (* __restrict__ s_h)[NNODE],
    float* __restrict__ s_rh,
    const float* __restrict__ Wg, const float* __restrict__ Bg,
    const float* __restrict__ Wc, const float* __restrict__ Cb,
    bool act, int n, int c1, int c2, float v, float vv,
    float* __restrict__ hreg, float o)
{
#pragma unroll
    for (int l = 0; l < 3; ++l) {
        __syncthreads();   // s_o / s_h[l] ready for gathers
        float oc1 = 0.f, oc2 = 0.f, hc1 = 0.f, hc2 = 0.f;
        if (act) {
            oc1 = s_o[c1]; oc2 = s_o[c2];
            hc1 = s_h[l][c1]; hc2 = s_h[l][c2];
        }
        const float hn = hreg[l];
        const float* W = Wg + l * 12;
        const float bgr = Bg[2 * l], bgu = Bg[2 * l + 1];
        float f1 = v * oc1, f2 = vv * oc2 - o;
        float f4 = v * hc1, f5 = vv * hc2 - hn;
        float r = fsigd(o*W[0] + f1*W[2] + f2*W[4] + hn*W[6] + f4*W[8] + f5*W[10] + bgr);
        float u = fsigd(o*W[1] + f1*W[3] + f2*W[5] + hn*W[7] + f4*W[9] + f5*W[11] + bgu);
        float rhn = r * hn;
        if (act) s_rh[n] = rhn;
        __syncthreads();   // rh visible
        float rhc1 = 0.f, rhc2 = 0.f;
        if (act) { rhc1 = s_rh[c1]; rhc2 = s_rh[c2]; }
        const float* C = Wc + l * 6;
        float cnd = ftanhd(o*C[0] + f1*C[1] + f2*C[2]
                           + rhn*C[3] + (v*rhc1)*C[4] + (vv*rhc2 - rhn)*C[5] + Cb[l]);
        float hnew = u * hn + (1.f - u) * cnd;
        hreg[l] = hnew;
        if (act) { s_h[l][n] = hnew; if (l < 2) s_o[n] = hnew; }
        o = hnew;
    }
    return o;
}

__global__ __launch_bounds__(384) void decode_kernel(
    const float* __restrict__ rec,   // (B, N, T)
    const int*   __restrict__ colp, const float* __restrict__ vp,
    const float* __restrict__ egw, const float* __restrict__ egb,
    const float* __restrict__ ecw, const float* __restrict__ ecb,
    const float* __restrict__ dgw, const float* __restrict__ dgb,
    const float* __restrict__ dcw, const float* __restrict__ dcb,
    const float* __restrict__ pw,  const float* __restrict__ pb,
    float* __restrict__ outp)        // (B, N, T)
{
    __shared__ float s_o[NNODE];
    __shared__ float s_h[3][NNODE];
    __shared__ float s_rh[NNODE];
    __shared__ float s_v[NNODE];
    __shared__ int   s_c[NNODE];
    __shared__ float s_egw[36], s_egb[6], s_ecw[18], s_ecb[3];
    __shared__ float s_dgw[36], s_dgb[6], s_dcw[18], s_dcb[3];

    const int b = blockIdx.x;
    const int n = threadIdx.x;
    if (n < 36) { s_egw[n] = egw[n]; s_dgw[n] = dgw[n]; }
    if (n < 6)  { s_egb[n] = egb[n]; s_dgb[n] = dgb[n]; }
    if (n < 18) { s_ecw[n] = ecw[n]; s_dcw[n] = dcw[n]; }
    if (n < 3)  { s_ecb[n] = ecb[n]; s_dcb[n] = dcb[n]; }
    const bool act = n < NNODE;
    if (act) {
        s_c[n] = colp[b * NNODE + n];
        s_v[n] = vp[b * NNODE + n];
        s_h[0][n] = 0.f; s_h[1][n] = 0.f; s_h[2][n] = 0.f;
    }
    __syncthreads();
    int c1 = 0, c2 = 0; float v = 0.f, vv = 0.f;
    if (act) {
        c1 = s_c[n];
        c2 = s_c[c1];
        v  = s_v[n];
        vv = 2.f * v * s_v[c1];
    }
    const float projw = pw[0], projb = pb[0];
    float hreg[3] = {0.f, 0.f, 0.f};

    // encoder, one-step input prefetch
    float inp = act ? rec[((size_t)b * NNODE + n) * TT + 0] : 0.f;
    for (int t = 0; t < TT; ++t) {
        float nx = (act && t + 1 < TT) ? rec[((size_t)b * NNODE + n) * TT + t + 1] : 0.f;
        if (act) s_o[n] = inp;
        run3(s_o, s_h, s_rh, s_egw, s_egb, s_ecw, s_ecb, act, n, c1, c2, v, vv, hreg, inp);
        inp = nx;
    }
    // decoder, feedback = proj
    float dinp = 0.f;
    for (int t = 0; t < TT; ++t) {
        if (act) s_o[n] = dinp;
        float h3 = run3(s_o, s_h, s_rh, s_dgw, s_dgb, s_dcw, s_dcb,
                        act, n, c1, c2, v, vv, hreg, dinp);
        float proj = h3 * projw + projb;
        if (act) outp[((size_t)b * NNODE + n) * TT + t] = proj;
        dinp = proj;
    }
}

// ---------------- host launcher ---------------------------------------------
extern "C" void kernel_launch(void* const* d_in, const int* in_sizes, int n_in,
                              void* d_out, int out_size, void* d_ws, size_t ws_size,
                              hipStream_t stream)
{
    (void)in_sizes; (void)n_in; (void)out_size; (void)ws_size;
    const float* full_seq = (const float*)d_in[0];   // (M,64,8)
    const float* rec_seq  = (const float*)d_in[1];   // (32,360,64)
    const float* temp     = (const float*)d_in[3];
    const float* g0wih    = (const float*)d_in[4];
    const float* g0whh    = (const float*)d_in[5];
    const float* g0bih    = (const float*)d_in[6];
    const float* g0bhh    = (const float*)d_in[7];
    const float* gwih     = (const float*)d_in[8];   // (3,2,24,16)
    const float* gwhh     = (const float*)d_in[9];   // (3,2,24,8)
    const float* gbih     = (const float*)d_in[10];
    const float* gbhh     = (const float*)d_in[11];
    const float* l1w      = (const float*)d_in[12];
    const float* l1b      = (const float*)d_in[13];
    const float* l2w      = (const float*)d_in[14];
    const float* l2b      = (const float*)d_in[15];
    const float* enc_gw   = (const float*)d_in[16];
    const float* enc_gb   = (const float*)d_in[17];
    const float* enc_cw   = (const float*)d_in[18];
    const float* enc_cb   = (const float*)d_in[19];
    const float* dec_gw   = (const float*)d_in[20];
    const float* dec_gb   = (const float*)d_in[21];
    const float* dec_cw   = (const float*)d_in[22];
    const float* dec_cb   = (const float*)d_in[23];
    const float* proj_w   = (const float*)d_in[24];
    const float* proj_b   = (const float*)d_in[25];
    float* outp = (float*)d_out;

    // ws: small-first; bufA+bufB ping-pong = 94.85 MB total (proven size)
    float* ws   = (float*)d_ws;
    float* feat = ws;                                     // (M,8)
    float* vbuf = feat + (size_t)M_SEQ * 8;               // (M,)
    int*   cbuf = (int*)(vbuf + M_SEQ);                   // (M,)
    float* bufA = (float*)(cbuf + M_SEQ);                 // (M,64,16)
    float* bufB = bufA + (size_t)M_SEQ * TT * 16;         // (M,64,16)

    const int ggru = (M_SEQ * 2 * 8) / 256;   // 720 blocks
    gru_fused<8><<<ggru, 256, 0, stream>>>(full_seq, g0wih, g0whh, g0bih, g0bhh, bufA);
    gru_fused<16><<<ggru, 256, 0, stream>>>(bufA, gwih + 0 * 768, gwhh + 0 * 384,
                                            gbih + 0 * 48, gbhh + 0 * 48, bufB);
    gru_fused<16><<<ggru, 256, 0, stream>>>(bufB, gwih + 1 * 768, gwhh + 1 * 384,
                                            gbih + 1 * 48, gbhh + 1 * 48, bufA);
    gru_fused<16><<<ggru, 256, 0, stream>>>(bufA, gwih + 2 * 768, gwhh + 2 * 384,
                                            gbih + 2 * 48, gbhh + 2 * 48, bufB);
    feat_kernel<<<M_SEQ / 256, 256, 0, stream>>>(bufB, l1w, l1b, l2w, l2b, feat);
    adj_kernel<<<(NB * NNODE) / 4, 256, 0, stream>>>(feat, temp, cbuf, vbuf);
    decode_kernel<<<NB, 384, 0, stream>>>(rec_seq, cbuf, vbuf,
                                          enc_gw, enc_gb, enc_cw, enc_cb,
                                          dec_gw, dec_gb, dec_cw, dec_cb,
                                          proj_w, proj_b, outp);
}

// Round 13
// 563.533 us; speedup vs baseline: 1.1598x; 1.1598x over previous
//
#include <hip/hip_runtime.h>
#include <math.h>

#define M_SEQ 11520   // B*N
#define NNODE 360
#define NB    32
#define TT    64

// adj path: libm-accurate — gumbel/argmax pipeline bit-identical to proven state.
// GRU + decode: fast hardware exp (R12: absmax bit-unchanged).
__device__ __forceinline__ float fsigd(float x)  { return 1.0f / (1.0f + __expf(-x)); }
__device__ __forceinline__ float ftanhd(float x) { return 1.0f - 2.0f / (__expf(2.0f * x) + 1.0f); }

// ---------------- JAX threefry2x32, key=(0,42), partitionable, bits=y0^y1 ----
__device__ __forceinline__ unsigned rotl32(unsigned x, int n) { return (x << n) | (x >> (32 - n)); }

__device__ __forceinline__ void tf2x32(unsigned& x0, unsigned& x1)
{
    const unsigned k0 = 0u, k1 = 42u, k2 = 0u ^ 42u ^ 0x1BD11BDAu;
    x0 += k0; x1 += k1;
#define R4(a,b,c,d) \
    x0 += x1; x1 = rotl32(x1,a); x1 ^= x0; \
    x0 += x1; x1 = rotl32(x1,b); x1 ^= x0; \
    x0 += x1; x1 = rotl32(x1,c); x1 ^= x0; \
    x0 += x1; x1 = rotl32(x1,d); x1 ^= x0;
    R4(13,15,26,6)   x0 += k1; x1 += k2 + 1u;
    R4(17,29,16,24)  x0 += k2; x1 += k0 + 2u;
    R4(13,15,26,6)   x0 += k0; x1 += k1 + 3u;
    R4(17,29,16,24)  x0 += k1; x1 += k2 + 4u;
    R4(13,15,26,6)   x0 += k2; x1 += k0 + 5u;
#undef R4
}

__device__ __forceinline__ float jax_uniform(unsigned idx)
{
    unsigned x0 = 0u, x1 = idx;
    tf2x32(x0, x1);
    unsigned bits = x0 ^ x1;          // VERIFIED R5
    return __uint_as_float((bits >> 9) | 0x3f800000u) - 1.0f;
}

// broadcast within aligned 8-lane group via static-pattern ds_swizzle.
template<int K>
__device__ __forceinline__ void swz_fma(float h, const float* w0, const float* w1,
                                        const float* w2, float& g0, float& g1, float& g2)
{
    float hk = __int_as_float(
        __builtin_amdgcn_ds_swizzle(__float_as_int(h), (K << 5) | 0x18));
    g0 += hk * w0[K];
    g1 += hk * w1[K];
    g2 += hk * w2[K];
    if constexpr (K < 7)
        swz_fma<K + 1>(h, w0, w1, w2, g0, g1, g2);
}

// ---------------- GRU helpers (h-independent x-path separated) --------------
template<int I>
__device__ __forceinline__ void ldx(float* __restrict__ xv, const float* __restrict__ p)
{
    const float4* p4 = reinterpret_cast<const float4*>(p);
#pragma unroll
    for (int q = 0; q < I / 4; ++q) {
        float4 f = p4[q];
        xv[4*q] = f.x; xv[4*q+1] = f.y; xv[4*q+2] = f.z; xv[4*q+3] = f.w;
    }
}

template<int I>
__device__ __forceinline__ void xgates(const float* __restrict__ xv,
    const float* wx0, const float* wx1, const float* wx2,
    float bx0, float bx1, float bx2, float& xr, float& xz, float& xn)
{
    xr = bx0; xz = bx1; xn = bx2;   // same accumulation order as R12 -> bit-identical
#pragma unroll
    for (int k = 0; k < I; ++k) {
        xr += xv[k] * wx0[k];
        xz += xv[k] * wx1[k];
        xn += xv[k] * wx2[k];
    }
}

__device__ __forceinline__ float hstep(float h, float xr, float xz, float xn,
    const float* w0, const float* w1, const float* w2,
    float bh0, float bh1, float bh2)
{
    float gh0 = bh0, gh1 = bh1, gh2 = bh2;
    swz_fma<0>(h, w0, w1, w2, gh0, gh1, gh2);
    float r  = fsigd(xr + gh0);
    float z  = fsigd(xz + gh1);
    float nn = ftanhd(xn + r * gh2);
    return (1.f - z) * nn + z * h;
}

// ---------------- fused bidirectional GRU layer, 2-deep x pipeline ----------
template<int I>
__global__ __launch_bounds__(256) void gru_fused(
    const float* __restrict__ x,    // (M,64,I)
    const float* __restrict__ wih,  // (2,24,I)
    const float* __restrict__ whh,  // (2,24,8)
    const float* __restrict__ bih,  // (2,24)
    const float* __restrict__ bhh,  // (2,24)
    float* __restrict__ out)        // (M,64,16), dir writes its 8-half
{
    const int tid = blockIdx.x * 256 + threadIdx.x;
    const int j   = tid & 7;
    const int md  = tid >> 3;
    if (md >= M_SEQ * 2) return;
    const int m = md >> 1, dir = md & 1;

    float wx0[I], wx1[I], wx2[I];
    const float* WI = wih + dir * 24 * I;
#pragma unroll
    for (int k = 0; k < I; ++k) {
        wx0[k] = WI[j * I + k];
        wx1[k] = WI[(8 + j) * I + k];
        wx2[k] = WI[(16 + j) * I + k];
    }
    float w0[8], w1[8], w2[8];
    const float* WH = whh + dir * 192;
#pragma unroll
    for (int k = 0; k < 8; ++k) {
        w0[k] = WH[j * 8 + k];
        w1[k] = WH[(8 + j) * 8 + k];
        w2[k] = WH[(16 + j) * 8 + k];
    }
    const float bx0 = bih[dir*24 + j], bx1 = bih[dir*24 + 8 + j], bx2 = bih[dir*24 + 16 + j];
    const float bh0 = bhh[dir*24 + j], bh1 = bhh[dir*24 + 8 + j], bh2 = bhh[dir*24 + 16 + j];

    const float* xm = x + (size_t)m * TT * I;
    float* om = out + (size_t)m * TT * 16 + dir * 8 + j;

    const int tstep = dir ? -1 : 1;
    const int tbase = dir ? TT - 1 : 0;

    float h = 0.f;
    float xva[I], xvb[I];
    ldx<I>(xva, xm + (tbase) * I);                 // t(0)
    ldx<I>(xvb, xm + (tbase + tstep) * I);         // t(1)
    float cr, cz, cn;
    xgates<I>(xva, wx0, wx1, wx2, bx0, bx1, bx2, cr, cz, cn);   // gates(t(0))

    for (int tt = 0; tt < TT; tt += 2) {
        const int t0 = tbase + tstep * tt;
        const int t1 = t0 + tstep;
        // prefetch t(tt+2) into the slot whose data is already in c-gates
        if (tt + 2 < TT) ldx<I>(xva, xm + (t0 + 2 * tstep) * I);
        // gates(t(tt+1)) — h-independent, overlaps the recurrence stalls
        float nr, nz, nn;
        xgates<I>(xvb, wx0, wx1, wx2, bx0, bx1, bx2, nr, nz, nn);
        h = hstep(h, cr, cz, cn, w0, w1, w2, bh0, bh1, bh2);
        om[t0 * 16] = h;
        // prefetch t(tt+3); xvb's content was consumed into n-gates above
        if (tt + 3 < TT) ldx<I>(xvb, xm + (t0 + 3 * tstep) * I);
        h = hstep(h, nr, nz, nn, w0, w1, w2, bh0, bh1, bh2);
        om[t1 * 16] = h;
        // gates(t(tt+2)) from xva — placed last: max load->use distance
        xgates<I>(xva, wx0, wx1, wx2, bx0, bx1, bx2, cr, cz, cn);
    }
}

// ---------------- feat MLP (pure FMA) ---------------------------------------
__global__ void feat_kernel(const float* __restrict__ gout,
                            const float* __restrict__ l1w, const float* __restrict__ l1b,
                            const float* __restrict__ l2w, const float* __restrict__ l2b,
                            float* __restrict__ feat)
{
    int m = blockIdx.x * blockDim.x + threadIdx.x;
    if (m >= M_SEQ) return;
    const float* xp = gout + (size_t)m * TT * 16 + (TT - 1) * 16;
    float xv[16];
#pragma unroll
    for (int i = 0; i < 16; ++i) xv[i] = xp[i];
    float h1[8];
#pragma unroll
    for (int o = 0; o < 8; ++o) {
        float a = 0.f;
#pragma unroll
        for (int f = 0; f < 16; ++f) a += xv[f] * l1w[o * 16 + f];
        a += l1b[o];
        h1[o] = (a >= 0.f) ? a : 0.2f * a;
    }
#pragma unroll
    for (int o = 0; o < 8; ++o) {
        float a = 0.f;
#pragma unroll
        for (int f = 0; f < 8; ++f) a += h1[f] * l2w[o * 8 + f];
        feat[(size_t)m * 8 + o] = a + l2b[o];
    }
}

// ---------------- adjacency (libm — bit-identical to proven state) ----------
__global__ void adj_kernel(const float* __restrict__ feat,
                           const float* __restrict__ tptr,
                           int* __restrict__ colp, float* __restrict__ vp)
{
    const int gw   = (blockIdx.x * blockDim.x + threadIdx.x) >> 6;
    const int lane = threadIdx.x & 63;
    if (gw >= NB * NNODE) return;
    const int b = gw / NNODE;
    const int n = gw - b * NNODE;
    const float T = tptr[0];
    const float* fb = feat + (size_t)b * NNODE * 8;
    float fn[8];
#pragma unroll
    for (int k = 0; k < 8; ++k) fn[k] = fb[(size_t)n * 8 + k];

    float sv[6];
    float mval = -3.0e38f; int midx = 1 << 30;
#pragma unroll
    for (int s = 0; s < 6; ++s) {
        int p = s * 64 + lane;
        float xs = -3.0e38f;
        if (p < NNODE) {
            const float* fp = fb + (size_t)p * 8;
            float d = 0.f;
#pragma unroll
            for (int k = 0; k < 8; ++k) d += fn[k] * fp[k];
            unsigned idx = (unsigned)gw * 360u + (unsigned)p;
            float u   = jax_uniform(idx);
            float gum = -logf(-logf(u + 1e-10f) + 1e-10f);
            xs = (d + gum) / T;
            if (xs > mval) { mval = xs; midx = p; }
        }
        sv[s] = xs;
    }
    for (int off = 32; off > 0; off >>= 1) {   // ties -> smaller index
        float ov = __shfl_xor(mval, off);
        int   oi = __shfl_xor(midx, off);
        if (ov > mval || (ov == mval && oi < midx)) { mval = ov; midx = oi; }
    }
    float ssum = 0.f;
#pragma unroll
    for (int s = 0; s < 6; ++s) {
        int p = s * 64 + lane;
        if (p < NNODE) ssum += expf(sv[s] - mval);
    }
    for (int off = 32; off > 0; off >>= 1) ssum += __shfl_xor(ssum, off);
    if (lane == 0) {
        float ys = 1.0f / ssum;
        float v  = ys + (1.0f - ys);
        if (midx == n) v = 0.0f;
        colp[gw] = midx;
        vp[gw]   = v;
    }
}

// ---------------- DCGRU 3-layer step: R11-proven structure ------------------
__device__ __forceinline__ float run3(
    float* __restrict__ s_o, float (* __restrict__ s_h)[NNODE],
    float* __restrict__ s_rh,
    const float* __restrict__ Wg, const float* __restrict__ Bg,
    const float* __restrict__ Wc, const float* __restrict__ Cb,
    bool act, int n, int c1, int c2, float v, float vv,
    float* __restrict__ hreg, float o)
{
#pragma unroll
    for (int l = 0; l < 3; ++l) {
        __syncthreads();   // s_o / s_h[l] ready for gathers
        float oc1 = 0.f, oc2 = 0.f, hc1 = 0.f, hc2 = 0.f;
        if (act) {
            oc1 = s_o[c1]; oc2 = s_o[c2];
            hc1 = s_h[l][c1]; hc2 = s_h[l][c2];
        }
        const float hn = hreg[l];
        const float* W = Wg + l * 12;
        const float bgr = Bg[2 * l], bgu = Bg[2 * l + 1];
        float f1 = v * oc1, f2 = vv * oc2 - o;
        float f4 = v * hc1, f5 = vv * hc2 - hn;
        float r = fsigd(o*W[0] + f1*W[2] + f2*W[4] + hn*W[6] + f4*W[8] + f5*W[10] + bgr);
        float u = fsigd(o*W[1] + f1*W[3] + f2*W[5] + hn*W[7] + f4*W[9] + f5*W[11] + bgu);
        float rhn = r * hn;
        if (act) s_rh[n] = rhn;
        __syncthreads();   // rh visible
        float rhc1 = 0.f, rhc2 = 0.f;
        if (act) { rhc1 = s_rh[c1]; rhc2 = s_rh[c2]; }
        const float* C = Wc + l * 6;
        float cnd = ftanhd(o*C[0] + f1*C[1] + f2*C[2]
                           + rhn*C[3] + (v*rhc1)*C[4] + (vv*rhc2 - rhn)*C[5] + Cb[l]);
        float hnew = u * hn + (1.f - u) * cnd;
        hreg[l] = hnew;
        if (act) { s_h[l][n] = hnew; if (l < 2) s_o[n] = hnew; }
        o = hnew;
    }
    return o;
}

__global__ __launch_bounds__(384) void decode_kernel(
    const float* __restrict__ rec,   // (B, N, T)
    const int*   __restrict__ colp, const float* __restrict__ vp,
    const float* __restrict__ egw, const float* __restrict__ egb,
    const float* __restrict__ ecw, const float* __restrict__ ecb,
    const float* __restrict__ dgw, const float* __restrict__ dgb,
    const float* __restrict__ dcw, const float* __restrict__ dcb,
    const float* __restrict__ pw,  const float* __restrict__ pb,
    float* __restrict__ outp)        // (B, N, T)
{
    __shared__ float s_o[NNODE];
    __shared__ float s_h[3][NNODE];
    __shared__ float s_rh[NNODE];
    __shared__ float s_v[NNODE];
    __shared__ int   s_c[NNODE];
    __shared__ float s_egw[36], s_egb[6], s_ecw[18], s_ecb[3];
    __shared__ float s_dgw[36], s_dgb[6], s_dcw[18], s_dcb[3];

    const int b = blockIdx.x;
    const int n = threadIdx.x;
    if (n < 36) { s_egw[n] = egw[n]; s_dgw[n] = dgw[n]; }
    if (n < 6)  { s_egb[n] = egb[n]; s_dgb[n] = dgb[n]; }
    if (n < 18) { s_ecw[n] = ecw[n]; s_dcw[n] = dcw[n]; }
    if (n < 3)  { s_ecb[n] = ecb[n]; s_dcb[n] = dcb[n]; }
    const bool act = n < NNODE;
    if (act) {
        s_c[n] = colp[b * NNODE + n];
        s_v[n] = vp[b * NNODE + n];
        s_h[0][n] = 0.f; s_h[1][n] = 0.f; s_h[2][n] = 0.f;
    }
    __syncthreads();
    int c1 = 0, c2 = 0; float v = 0.f, vv = 0.f;
    if (act) {
        c1 = s_c[n];
        c2 = s_c[c1];
        v  = s_v[n];
        vv = 2.f * v * s_v[c1];
    }
    const float projw = pw[0], projb = pb[0];
    float hreg[3] = {0.f, 0.f, 0.f};

    // encoder, one-step input prefetch
    float inp = act ? rec[((size_t)b * NNODE + n) * TT + 0] : 0.f;
    for (int t = 0; t < TT; ++t) {
        float nx = (act && t + 1 < TT) ? rec[((size_t)b * NNODE + n) * TT + t + 1] : 0.f;
        if (act) s_o[n] = inp;
        run3(s_o, s_h, s_rh, s_egw, s_egb, s_ecw, s_ecb, act, n, c1, c2, v, vv, hreg, inp);
        inp = nx;
    }
    // decoder, feedback = proj
    float dinp = 0.f;
    for (int t = 0; t < TT; ++t) {
        if (act) s_o[n] = dinp;
        float h3 = run3(s_o, s_h, s_rh, s_dgw, s_dgb, s_dcw, s_dcb,
                        act, n, c1, c2, v, vv, hreg, dinp);
        float proj = h3 * projw + projb;
        if (act) outp[((size_t)b * NNODE + n) * TT + t] = proj;
        dinp = proj;
    }
}

// ---------------- host launcher ---------------------------------------------
extern "C" void kernel_launch(void* const* d_in, const int* in_sizes, int n_in,
                              void* d_out, int out_size, void* d_ws, size_t ws_size,
                              hipStream_t stream)
{
    (void)in_sizes; (void)n_in; (void)out_size; (void)ws_size;
    const float* full_seq = (const float*)d_in[0];   // (M,64,8)
    const float* rec_seq  = (const float*)d_in[1];   // (32,360,64)
    const float* temp     = (const float*)d_in[3];
    const float* g0wih    = (const float*)d_in[4];
    const float* g0whh    = (const float*)d_in[5];
    const float* g0bih    = (const float*)d_in[6];
    const float* g0bhh    = (const float*)d_in[7];
    const float* gwih     = (const float*)d_in[8];   // (3,2,24,16)
    const float* gwhh     = (const float*)d_in[9];   // (3,2,24,8)
    const float* gbih     = (const float*)d_in[10];
    const float* gbhh     = (const float*)d_in[11];
    const float* l1w      = (const float*)d_in[12];
    const float* l1b      = (const float*)d_in[13];
    const float* l2w      = (const float*)d_in[14];
    const float* l2b      = (const float*)d_in[15];
    const float* enc_gw   = (const float*)d_in[16];
    const float* enc_gb   = (const float*)d_in[17];
    const float* enc_cw   = (const float*)d_in[18];
    const float* enc_cb   = (const float*)d_in[19];
    const float* dec_gw   = (const float*)d_in[20];
    const float* dec_gb   = (const float*)d_in[21];
    const float* dec_cw   = (const float*)d_in[22];
    const float* dec_cb   = (const float*)d_in[23];
    const float* proj_w   = (const float*)d_in[24];
    const float* proj_b   = (const float*)d_in[25];
    float* outp = (float*)d_out;

    // ws: small-first; bufA+bufB ping-pong = 94.85 MB total (proven size)
    float* ws   = (float*)d_ws;
    float* feat = ws;                                     // (M,8)
    float* vbuf = feat + (size_t)M_SEQ * 8;               // (M,)
    int*   cbuf = (int*)(vbuf + M_SEQ);                   // (M,)
    float* bufA = (float*)(cbuf + M_SEQ);                 // (M,64,16)
    float* bufB = bufA + (size_t)M_SEQ * TT * 16;         // (M,64,16)

    const int ggru = (M_SEQ * 2 * 8) / 256;   // 720 blocks
    gru_fused<8><<<ggru, 256, 0, stream>>>(full_seq, g0wih, g0whh, g0bih, g0bhh, bufA);
    gru_fused<16><<<ggru, 256, 0, stream>>>(bufA, gwih + 0 * 768, gwhh + 0 * 384,
                                            gbih + 0 * 48, gbhh + 0 * 48, bufB);
    gru_fused<16><<<ggru, 256, 0, stream>>>(bufB, gwih + 1 * 768, gwhh + 1 * 384,
                                            gbih + 1 * 48, gbhh + 1 * 48, bufA);
    gru_fused<16><<<ggru, 256, 0, stream>>>(bufA, gwih + 2 * 768, gwhh + 2 * 384,
                                            gbih + 2 * 48, gbhh + 2 * 48, bufB);
    feat_kernel<<<M_SEQ / 256, 256, 0, stream>>>(bufB, l1w, l1b, l2w, l2b, feat);
    adj_kernel<<<(NB * NNODE) / 4, 256, 0, stream>>>(feat, temp, cbuf, vbuf);
    decode_kernel<<<NB, 384, 0, stream>>>(rec_seq, cbuf, vbuf,
                                          enc_gw, enc_gb, enc_cw, enc_cb,
                                          dec_gw, dec_gb, dec_cw, dec_cb,
                                          proj_w, proj_b, outp);
}